// Round 4
// baseline (303.212 us; speedup 1.0000x reference)
//
#include <hip/hip_runtime.h>
#include <hip/hip_bf16.h>
#include <math.h>

#define WW 1024
#define HH 1024
#define TI 128
#define TJ 128
#define HALO_I 160     // hr (x) extent in LDS, padded; valid hr < 148
#define HALO_J 148     // hc (y) extent
#define PITCH_T 168    // ThT row pitch in elems; 336B -> conflict-free b128 phases
#define AOFF 448       // float offset of A-pattern table in ws
#define META_BASE_F 22016                       // float offset of base-index array
#define META_WTS_F  (META_BASE_F + WW * HH)     // float offset of weights array (u64/pt)
#define WS_NEED_BYTES ((size_t)(META_WTS_F + 2 * WW * HH) * 4)

typedef short short8 __attribute__((ext_vector_type(8)));
typedef float float16 __attribute__((ext_vector_type(16)));

__device__ __forceinline__ unsigned short f2bf(float f) {
    union { float f; unsigned int u; } c; c.f = f;
    unsigned int u = c.u;
    return (unsigned short)((u + 0x7FFFu + ((u >> 16) & 1u)) >> 16);
}
__device__ __forceinline__ unsigned short f2h(float f) {
    union { _Float16 h; unsigned short u; } c; c.h = (_Float16)f; return c.u;
}
__device__ __forceinline__ float h2f(unsigned short u) {
    union { _Float16 h; unsigned short u; } c; c.u = u; return (float)c.h;
}

// ---------------- prep: PSF normalize + scalar params ----------------
__global__ void prep_kernel(const float* __restrict__ raw_psf,
                            const float* __restrict__ x0p, const float* __restrict__ y0p,
                            const float* __restrict__ raw_b, const float* __restrict__ raw_rc,
                            const float* __restrict__ raw_sub,
                            float* __restrict__ ws) {
    __shared__ float red[512];
    int t = threadIdx.x;
    float v = 0.f;
    if (t < 441) v = fmaxf(raw_psf[t], 0.f);
    red[t] = v;
    __syncthreads();
    for (int s = 256; s > 0; s >>= 1) {
        if (t < s) red[t] += red[t + s];
        __syncthreads();
    }
    float sum = fmaxf(red[0], 1e-12f);
    if (t < 441) ws[t] = v / sum;
    if (t == 0) {
        float b  = log1pf(expf(raw_b[0]))  + 1e-8f;
        float rc = log1pf(expf(raw_rc[0])) + 1e-8f;
        ws[441] = b;
        ws[442] = 1e-12f + rc * rc;
        ws[443] = 0.25f * tanhf(raw_sub[0]);
        ws[444] = 0.25f * tanhf(raw_sub[1]);
        ws[445] = x0p[0];
        ws[446] = y0p[0];
    }
}

// ---------------- A-pattern Toeplitz table (parallel, 21 blocks) ----------------
// Apat[v][d][l][q] = P_bf16[16d + k0 + q - m][v], m=l&31, k0=8*(l>>5)
__global__ void abuild_kernel(float* __restrict__ ws) {
    int g = blockIdx.x * 256 + threadIdx.x;     // g = v*256 + d*64 + l, g < 5376
    int vv = g >> 8;
    int r  = g & 255;
    int d  = r >> 6;
    int l  = r & 63;
    int m  = l & 31;
    int k0 = (l >> 5) << 3;
    short8 o8;
#pragma unroll
    for (int q = 0; q < 8; ++q) {
        int u = 16 * d + k0 + q - m;
        unsigned short pv = 0;
        if ((unsigned)u <= 20u) pv = f2bf(ws[u * 21 + vv]);
        o8[q] = (short)pv;
    }
    ((short8*)(ws + AOFF))[g] = o8;
}

// ---------------- warp meta: base idx + edge bits + 4 edge-masked fp16 weights ----
__global__ void meta_kernel(const float* __restrict__ pp,
                            unsigned int* __restrict__ baseA,
                            ushort4* __restrict__ wtsA) {
    int p = blockIdx.x * 256 + threadIdx.x;     // p < 1<<20
    int J = p >> 10;          // y index
    int I = p & 1023;         // x index
    const float bpar = pp[441];
    const float rc2  = pp[442];
    const float sub0 = pp[443];
    const float sub1 = pp[444];
    const float x0   = pp[445];
    const float y0   = pp[446];
    const float SSTEP = 2.0f / 1023.0f;

    float xv = fmaf((float)I, SSTEP, -1.0f);
    float yv = fmaf((float)J, SSTEP, -1.0f);
    float dx = xv - x0;
    float dy = yv - y0;
    float s = bpar * __builtin_amdgcn_rsqf(dx * dx + dy * dy + rc2);
    float gx = xv - dx * s + sub0;
    float gy = yv - dy * s + sub1;
    float ix = (gx + 1.0f) * (0.5f * 1023.0f);
    float iy = (gy + 1.0f) * (0.5f * 1023.0f);
    float fx = floorf(ix), fy = floorf(iy);
    float wx1 = ix - fx, wy1 = iy - fy;
    int xi0 = (int)fx, yi0 = (int)fy;
    int xi1 = xi0 + 1, yi1 = yi0 + 1;
    int xc0 = min(max(xi0, 0), WW - 1);
    int xc1 = min(max(xi1, 0), WW - 1);
    int yc0 = min(max(yi0, 0), HH - 1);
    int yc1 = min(max(yi1, 0), HH - 1);
    bool vx0 = (unsigned)xi0 < WW, vx1 = (unsigned)xi1 < WW;
    bool vy0 = (unsigned)yi0 < HH, vy1 = (unsigned)yi1 < HH;
    float ax0 = vx0 ? (1.f - wx1) : 0.f;
    float ax1 = vx1 ? wx1 : 0.f;
    float ay0 = vy0 ? (1.f - wy1) : 0.f;
    float ay1 = vy1 ? wy1 : 0.f;
    unsigned int base = (unsigned)(yc0 * WW + xc0);
    base |= ((unsigned)(xc1 - xc0)) << 24;   // x-offset bit (0 at edges)
    base |= ((unsigned)(yc1 - yc0)) << 25;   // y-offset bit
    baseA[p] = base;
    wtsA[p] = make_ushort4(f2h(ax0), f2h(ax1), f2h(ay0), f2h(ay1));
}

// ---------------- fused (meta path): gather-lerp fill -> bf16 LDS -> MFMA conv ----
__global__ __launch_bounds__(256, 2) void fused_meta_kernel(
        const float* __restrict__ src, const float* __restrict__ pp,
        const unsigned int* __restrict__ baseA, const ushort4* __restrict__ wtsA,
        float* __restrict__ out) {
    __shared__ unsigned short ThT[HALO_J * PITCH_T];   // [hc][hr], bf16

    const int tid = threadIdx.x;
    const int j0 = blockIdx.x * TJ;
    const int i0 = blockIdx.y * TI;
    const int b0 = blockIdx.z;
    const float* sb = src + (size_t)b0 * (HH * (size_t)WW);

    // ---- fill transposed halo tile from meta (2 adjacent hr per thread) ----
    for (int p = tid; p < (HALO_J * HALO_I) / 2; p += 256) {
        int idx2 = p << 1;
        int hc = idx2 / HALO_I;
        int hr0 = idx2 - hc * HALO_I;
        int J = j0 - 10 + hc;
        unsigned int pk = 0;
        bool rowv = (unsigned)J < (unsigned)HH;
        float vpt[2];
#pragma unroll
        for (int e = 0; e < 2; ++e) {
            int hr = hr0 + e;
            int I = i0 - 10 + hr;
            float val = 0.f;
            if (rowv && hr < 148 && (unsigned)I < (unsigned)WW) {
                int m = J * WW + I;
                unsigned int b = baseA[m];
                ushort4 w = wtsA[m];
                unsigned int b0i = b & 0xFFFFFu;
                unsigned int dxo = (b >> 24) & 1u;
                unsigned int dyo = (b >> 25) & 1u;
                const float* q = sb + b0i;
                unsigned int o10 = dyo << 10;
                float v00 = q[0];
                float v01 = q[dxo];
                float v10 = q[o10];
                float v11 = q[o10 + dxo];
                float ax0 = h2f(w.x), ax1 = h2f(w.y);
                float ay0 = h2f(w.z), ay1 = h2f(w.w);
                val = ay0 * fmaf(ax0, v00, ax1 * v01) +
                      ay1 * fmaf(ax0, v10, ax1 * v11);
            }
            vpt[e] = val;
        }
        pk = (unsigned int)f2bf(vpt[0]) | ((unsigned int)f2bf(vpt[1]) << 16);
        *(unsigned int*)&ThT[hc * PITCH_T + hr0] = pk;
    }
    __syncthreads();

    // ---- MFMA conv: wave wv owns j in [32*wv, 32*wv+32), all 4 M-blocks ----
    const int lane = tid & 63;
    const int wv = tid >> 6;
    const int nrow = lane & 31;
    const int khalf = lane >> 5;

    float16 acc[4];
#pragma unroll
    for (int m = 0; m < 4; ++m)
#pragma unroll
        for (int q = 0; q < 16; ++q) acc[m][q] = 0.f;

    const short8* Aall = (const short8*)(pp + AOFF);

#define LD_A(vx, Af) do {                                                   \
        _Pragma("unroll") for (int d = 0; d < 4; ++d)                       \
            Af[d] = Aall[((vx) * 4 + d) * 64 + lane];                       \
    } while (0)
#define LD_B(vx, Bf) do {                                                   \
        const unsigned short* bp_ =                                         \
            &ThT[(32 * wv + nrow + (vx)) * PITCH_T + khalf * 8];            \
        _Pragma("unroll") for (int c = 0; c < 10; ++c)                      \
            Bf[c] = *(const short8*)&bp_[16 * c];                           \
    } while (0)
#define DO_MFMA(Af, Bf) do {                                                \
        _Pragma("unroll") for (int mq = 0; mq < 4; ++mq)                    \
            _Pragma("unroll") for (int d = 0; d < 4; ++d)                   \
                acc[mq] = __builtin_amdgcn_mfma_f32_32x32x16_bf16(          \
                    Af[d], Bf[2 * mq + d], acc[mq], 0, 0, 0);               \
    } while (0)

    short8 A0[4], A1[4], B0[10], B1[10];
    LD_A(0, A0); LD_B(0, B0);
#pragma unroll 1
    for (int vv = 0; vv < 10; ++vv) {
        int v = 2 * vv;
        LD_A(v + 1, A1); LD_B(v + 1, B1);
        DO_MFMA(A0, B0);
        LD_A(v + 2, A0); LD_B(v + 2, B0);
        DO_MFMA(A1, B1);
    }
    DO_MFMA(A0, B0);   // v = 20

#undef LD_A
#undef LD_B
#undef DO_MFMA

    // ---- epilogue: C/D layout col=lane&31, row=(reg&3)+8*(reg>>2)+4*(lane>>5) ----
    float* ob = out + (size_t)b0 * (WW * (size_t)HH);
    const int gj = j0 + 32 * wv + nrow;
#pragma unroll
    for (int mq = 0; mq < 4; ++mq) {
#pragma unroll
        for (int reg = 0; reg < 16; ++reg) {
            int row = (reg & 3) + 8 * (reg >> 2) + 4 * khalf;
            int gi = i0 + 32 * mq + row;
            ob[(size_t)gi * HH + gj] = acc[mq][reg];
        }
    }
}

// ---------------- fallback (inline warp math) if ws too small for meta ----------
__global__ __launch_bounds__(256, 2) void fused_inline_kernel(
        const float* __restrict__ src, const float* __restrict__ pp,
        float* __restrict__ out) {
    __shared__ unsigned short ThT[HALO_J * PITCH_T];
    const int tid = threadIdx.x;
    const int j0 = blockIdx.x * TJ;
    const int i0 = blockIdx.y * TI;
    const int b0 = blockIdx.z;
    const float bpar = pp[441];
    const float rc2  = pp[442];
    const float sub0 = pp[443];
    const float sub1 = pp[444];
    const float x0   = pp[445];
    const float y0   = pp[446];
    const float SSTEP = 2.0f / 1023.0f;
    const float* sb = src + (size_t)b0 * (HH * (size_t)WW);

    for (int p = tid; p < (HALO_J * HALO_I) / 2; p += 256) {
        int idx2 = p << 1;
        int hc = idx2 / HALO_I;
        int hr0 = idx2 - hc * HALO_I;
        unsigned int pk = 0;
#pragma unroll
        for (int e = 0; e < 2; ++e) {
            int hr = hr0 + e;
            int I = i0 - 10 + hr;
            int J = j0 - 10 + hc;
            float val = 0.f;
            if (hr < 148 && (unsigned)I < WW && (unsigned)J < HH) {
                float xv = fmaf((float)I, SSTEP, -1.0f);
                float yv = fmaf((float)J, SSTEP, -1.0f);
                float dx = xv - x0;
                float dy = yv - y0;
                float s = bpar * __builtin_amdgcn_rsqf(dx * dx + dy * dy + rc2);
                float gx = xv - dx * s + sub0;
                float gy = yv - dy * s + sub1;
                float ix = (gx + 1.0f) * (0.5f * 1023.0f);
                float iy = (gy + 1.0f) * (0.5f * 1023.0f);
                float fx = floorf(ix), fy = floorf(iy);
                float wx1 = ix - fx, wy1 = iy - fy;
                float wx0 = 1.f - wx1, wy0 = 1.f - wy1;
                int xi0 = (int)fx, yi0 = (int)fy;
                int xi1 = xi0 + 1, yi1 = yi0 + 1;
                int xc0 = min(max(xi0, 0), WW - 1);
                int xc1 = min(max(xi1, 0), WW - 1);
                int yc0 = min(max(yi0, 0), HH - 1);
                int yc1 = min(max(yi1, 0), HH - 1);
                bool vx0 = (unsigned)xi0 < WW, vx1 = (unsigned)xi1 < WW;
                bool vy0 = (unsigned)yi0 < HH, vy1 = (unsigned)yi1 < HH;
                float w00 = (vx0 && vy0) ? wy0 * wx0 : 0.f;
                float w01 = (vx1 && vy0) ? wy0 * wx1 : 0.f;
                float w10 = (vx0 && vy1) ? wy1 * wx0 : 0.f;
                float w11 = (vx1 && vy1) ? wy1 * wx1 : 0.f;
                val = sb[yc0 * WW + xc0] * w00 + sb[yc0 * WW + xc1] * w01 +
                      sb[yc1 * WW + xc0] * w10 + sb[yc1 * WW + xc1] * w11;
            }
            pk |= (unsigned int)f2bf(val) << (16 * e);
        }
        *(unsigned int*)&ThT[hc * PITCH_T + hr0] = pk;
    }
    __syncthreads();

    const int lane = tid & 63;
    const int wv = tid >> 6;
    const int nrow = lane & 31;
    const int khalf = lane >> 5;
    float16 acc[4];
#pragma unroll
    for (int m = 0; m < 4; ++m)
#pragma unroll
        for (int q = 0; q < 16; ++q) acc[m][q] = 0.f;
    const short8* Aall = (const short8*)(pp + AOFF);
#pragma unroll 1
    for (int v = 0; v < 21; ++v) {
        short8 Af[4];
#pragma unroll
        for (int d = 0; d < 4; ++d) Af[d] = Aall[(v * 4 + d) * 64 + lane];
        const unsigned short* bp = &ThT[(32 * wv + nrow + v) * PITCH_T + khalf * 8];
        short8 Bf[10];
#pragma unroll
        for (int c = 0; c < 10; ++c) Bf[c] = *(const short8*)&bp[16 * c];
#pragma unroll
        for (int mq = 0; mq < 4; ++mq)
#pragma unroll
            for (int d = 0; d < 4; ++d)
                acc[mq] = __builtin_amdgcn_mfma_f32_32x32x16_bf16(
                    Af[d], Bf[2 * mq + d], acc[mq], 0, 0, 0);
    }
    float* ob = out + (size_t)b0 * (WW * (size_t)HH);
    const int gj = j0 + 32 * wv + nrow;
#pragma unroll
    for (int mq = 0; mq < 4; ++mq)
#pragma unroll
        for (int reg = 0; reg < 16; ++reg) {
            int row = (reg & 3) + 8 * (reg >> 2) + 4 * khalf;
            int gi = i0 + 32 * mq + row;
            ob[(size_t)gi * HH + gj] = acc[mq][reg];
        }
}

extern "C" void kernel_launch(void* const* d_in, const int* in_sizes, int n_in,
                              void* d_out, int out_size, void* d_ws, size_t ws_size,
                              hipStream_t stream) {
    const float* src     = (const float*)d_in[0];
    const float* raw_psf = (const float*)d_in[1];
    const float* x0      = (const float*)d_in[2];
    const float* y0      = (const float*)d_in[3];
    const float* raw_b   = (const float*)d_in[4];
    const float* raw_rc  = (const float*)d_in[5];
    const float* raw_sub = (const float*)d_in[6];
    float* ws = (float*)d_ws;

    prep_kernel<<<1, 512, 0, stream>>>(raw_psf, x0, y0, raw_b, raw_rc, raw_sub, ws);
    abuild_kernel<<<21, 256, 0, stream>>>(ws);

    dim3 grid(HH / TJ, WW / TI, 16);   // (8, 8, 16)
    if (ws_size >= WS_NEED_BYTES) {
        unsigned int* baseA = (unsigned int*)(ws + META_BASE_F);
        ushort4* wtsA = (ushort4*)(ws + META_WTS_F);
        meta_kernel<<<(WW * HH) / 256, 256, 0, stream>>>(ws, baseA, wtsA);
        fused_meta_kernel<<<grid, 256, 0, stream>>>(src, ws, baseA, wtsA, (float*)d_out);
    } else {
        fused_inline_kernel<<<grid, 256, 0, stream>>>(src, ws, (float*)d_out);
    }
}